// Round 5
// baseline (197.566 us; speedup 1.0000x reference)
//
#include <hip/hip_runtime.h>

typedef unsigned short ushort_t;
typedef unsigned int uint_t;
typedef __attribute__((ext_vector_type(4))) float f32x4;
typedef __attribute__((ext_vector_type(8))) __bf16 bf16x8;

#define LAMBDA_INIT 0.7836057665316245f
#define ONE_MINUS_LI 0.21639423346837552f
#define QSCALE_LOG2E 0.25505654442552663f  // 32^-0.5 * log2(e)

__device__ inline ushort_t f2bf(float f) {
  union { float f; unsigned u; } v; v.f = f;
  unsigned r = (v.u + 0x7FFFu + ((v.u >> 16) & 1u)) >> 16;
  return (ushort_t)r;
}

// bare v_exp_f32 (args bounded, no libm range fixup needed)
__device__ inline float fexp2(float x) {
  float r;
  asm("v_exp_f32 %0, %1" : "=v"(r) : "v"(x));
  return r;
}

// pack 2 f32 -> 2 bf16 (RNE), lo in low half
__device__ inline uint_t cvtpk(float lo, float hi) {
  uint_t r;
  asm("v_cvt_pk_bf16_f32 %0, %1, %2" : "=v"(r) : "v"(lo), "v"(hi));
  return r;
}

__device__ inline f32x4 zero4() { f32x4 z = {0.f, 0.f, 0.f, 0.f}; return z; }

__device__ inline f32x4 mfma16(bf16x8 a, bf16x8 b, f32x4 c) {
  return __builtin_amdgcn_mfma_f32_16x16x32_bf16(a, b, c, 0, 0, 0);
}

__device__ inline void gload_lds16(const void* g, void* l) {
  __builtin_amdgcn_global_load_lds(
      (const __attribute__((address_space(1))) unsigned int*)g,
      (__attribute__((address_space(3))) unsigned int*)l, 16, 0, 0);
}

// ---------------- convert x (fp32 -> bf16) ----------------
__global__ __launch_bounds__(256) void cvt_f32_bf16(const float* __restrict__ in,
                                                    ushort_t* __restrict__ out, int n) {
  int i = (blockIdx.x * 256 + threadIdx.x) * 8;
  if (i >= n) return;
  float4 a = *(const float4*)(in + i);
  float4 b = *(const float4*)(in + i + 4);
  uint4 pack;
  pack.x = cvtpk(a.x, a.y);
  pack.y = cvtpk(a.z, a.w);
  pack.z = cvtpk(b.x, b.y);
  pack.w = cvtpk(b.z, b.w);
  *(uint4*)(out + i) = pack;
}

// ---------------- transpose W (KxN fp32) -> WT (NxK bf16) ----------------
__global__ __launch_bounds__(256) void transpose_to_bf16(const float* __restrict__ W,
                                                         ushort_t* __restrict__ WT,
                                                         int K, int N) {
  __shared__ float tile[32][33];
  int n0 = blockIdx.x * 32, k0 = blockIdx.y * 32;
  int tx = threadIdx.x & 31, ty = threadIdx.x >> 5;
#pragma unroll
  for (int j = 0; j < 4; ++j) {
    int k = k0 + ty + j * 8;
    tile[ty + j * 8][tx] = W[(size_t)k * N + n0 + tx];
  }
  __syncthreads();
#pragma unroll
  for (int j = 0; j < 4; ++j) {
    int n = n0 + ty + j * 8;
    WT[(size_t)n * K + k0 + tx] = f2bf(tile[tx][ty + j * 8]);
  }
}

// ---------------- GEMM: C[M,N] = A[M,K] * Bt[N,K]^T, bf16 in ----------------
template <int MODE>
__global__ __launch_bounds__(256) void gemm_bt(const ushort_t* __restrict__ A,
                                               const ushort_t* __restrict__ Bt,
                                               void* __restrict__ C,
                                               ushort_t* __restrict__ vt_out,
                                               const float* __restrict__ bias,
                                               int M, int N, int K) {
  __shared__ ushort_t As[128 * 32];
  __shared__ ushort_t Bs[128 * 32];
  const int tid = threadIdx.x;
  const int wave = tid >> 6, lane = tid & 63;
  const int wr = wave >> 1, wc = wave & 1;
  const int lg = lane >> 4, ll = lane & 15;
  const int row0 = blockIdx.x * 128, col0 = blockIdx.y * 128;

  f32x4 acc[4][4];
#pragma unroll
  for (int m = 0; m < 4; ++m)
#pragma unroll
    for (int n = 0; n < 4; ++n) acc[m][n] = zero4();

  for (int k0 = 0; k0 < K; k0 += 32) {
    __syncthreads();
#pragma unroll
    for (int i = 0; i < 2; ++i) {
      int c = tid + i * 256;
      int r = c >> 2, ko = (c & 3) << 3;
      gload_lds16(A + (size_t)(row0 + r) * K + k0 + ko,
                  (char*)As + (size_t)(wave * 64 + i * 256) * 16);
      gload_lds16(Bt + (size_t)(col0 + r) * K + k0 + ko,
                  (char*)Bs + (size_t)(wave * 64 + i * 256) * 16);
    }
    __syncthreads();
    bf16x8 af[4], bf[4];
#pragma unroll
    for (int m = 0; m < 4; ++m)
      af[m] = *(const bf16x8*)(As + (wr * 64 + m * 16 + ll) * 32 + (lg << 3));
#pragma unroll
    for (int n = 0; n < 4; ++n)
      bf[n] = *(const bf16x8*)(Bs + (wc * 64 + n * 16 + ll) * 32 + (lg << 3));
#pragma unroll
    for (int m = 0; m < 4; ++m)
#pragma unroll
      for (int n = 0; n < 4; ++n) acc[m][n] = mfma16(af[m], bf[n], acc[m][n]);
  }

#pragma unroll
  for (int m = 0; m < 4; ++m) {
#pragma unroll
    for (int n = 0; n < 4; ++n) {
      int gc = col0 + wc * 64 + n * 16 + ll;
      int gr0 = row0 + wr * 64 + m * 16 + (lg << 2);
      if (MODE == 0) {
#pragma unroll
        for (int j = 0; j < 4; ++j)
          ((float*)C)[(size_t)(gr0 + j) * N + gc] = acc[m][n][j] + bias[gc];
      } else {
        if (gc < 2048) {
          float sc = (gc < 1024) ? QSCALE_LOG2E : 1.0f;
#pragma unroll
          for (int j = 0; j < 4; ++j)
            ((ushort_t*)C)[(size_t)(gr0 + j) * 2048 + gc] = f2bf(acc[m][n][j] * sc);
        } else {
          // V columns -> transposed store, 4 consecutive n packed into 8B
          int hv = (gc - 2048) >> 6, dv = (gc - 2048) & 63;
          int bb = gr0 >> 11, nn = gr0 & 2047;
          uint2 w;
          w.x = cvtpk(acc[m][n][0], acc[m][n][1]);
          w.y = cvtpk(acc[m][n][2], acc[m][n][3]);
          *(uint2*)(vt_out + ((size_t)((bb * 16 + hv) * 64 + dv)) * 2048 + nn) = w;
        }
      }
    }
  }
}

// ---------------- differential flash attention ----------------
// QBLK=128: 4 waves x 2 q-subtiles of 16 rows. Swapped QK^T, static max,
// statically-unrolled double buffer (all LDS addrs loop-invariant).
__global__ __launch_bounds__(256) void diff_attn(const ushort_t* __restrict__ qk,
                                                 const ushort_t* __restrict__ vt,
                                                 ushort_t* __restrict__ o,
                                                 const float* __restrict__ lq1,
                                                 const float* __restrict__ lk1,
                                                 const float* __restrict__ lq2,
                                                 const float* __restrict__ lk2,
                                                 const float* __restrict__ subln) {
  const int qt = blockIdx.x, h = blockIdx.y, b = blockIdx.z;
  const int tid = threadIdx.x, wave = tid >> 6, lane = tid & 63;
  const int lg = lane >> 4, ll = lane & 15;

  const size_t qbase = (size_t)b * 2048 * 2048;
  const int cq1 = (h << 5), cq2 = 512 + (h << 5);
  const int ck1 = 1024 + (h << 5), ck2 = 1536 + (h << 5);
  const size_t vbase = (size_t)((b * 16 + h) * 64) * 2048;

  float sl1 = 0.f, sl2 = 0.f;
  for (int j = 0; j < 32; ++j) { sl1 += lq1[j] * lk1[j]; sl2 += lq2[j] * lk2[j]; }
  const float lam = __expf(sl1) - __expf(sl2) + LAMBDA_INIT;

  __shared__ ushort_t Ks[2][64 * 64];   // [kv r][8 chunks: 0-3 K1, 4-7 K2], XOR-8 swizzled
  __shared__ ushort_t Vs[2][64 * 64];   // [d r][8 t-chunks], XOR-8 swizzled
  __shared__ ushort_t Pl[4][16 * 72];   // per-wave P (reused by both subtiles, in-order DS)

  // Q fragments [pass][sub] (B-operand of swapped QK^T)
  const int qrow0 = qt * 128 + wave * 32 + ll;
  bf16x8 qf[2][2];
  qf[0][0] = *(const bf16x8*)(qk + qbase + (size_t)qrow0 * 2048 + cq1 + (lg << 3));
  qf[0][1] = *(const bf16x8*)(qk + qbase + (size_t)(qrow0 + 16) * 2048 + cq1 + (lg << 3));
  qf[1][0] = *(const bf16x8*)(qk + qbase + (size_t)qrow0 * 2048 + cq2 + (lg << 3));
  qf[1][1] = *(const bf16x8*)(qk + qbase + (size_t)(qrow0 + 16) * 2048 + cq2 + (lg << 3));

  f32x4 oacc[2][2][4];
#pragma unroll
  for (int p = 0; p < 2; ++p)
#pragma unroll
    for (int s = 0; s < 2; ++s)
#pragma unroll
      for (int nb = 0; nb < 4; ++nb) oacc[p][s][nb] = zero4();
  float lsum[2][2] = {{0.f, 0.f}, {0.f, 0.f}};
  ushort_t* Pw = &Pl[wave][0];

  // staging geometry: slot s -> row r = s>>3, lds chunk s&7 holds global chunk (s&7)^(r&7)
  const int s0 = tid, s1 = tid + 256;
  const int r0 = s0 >> 3, c0 = (s0 & 7) ^ (r0 & 7);
  const int r1 = s1 >> 3, c1 = (s1 & 7) ^ (r1 & 7);
  const int kc0 = ((c0 & 4) ? ck2 : ck1) + ((c0 & 3) << 3);
  const int kc1 = ((c1 & 4) ? ck2 : ck1) + ((c1 & 3) << 3);
  const int ub0 = (wave << 6) * 16;
  const int ub1 = ((wave << 6) + 256) * 16;

#define STAGE(buf, kv0)                                                                   \
  do {                                                                                    \
    gload_lds16(qk + qbase + (size_t)((kv0) + r0) * 2048 + kc0, (char*)Ks[buf] + ub0);    \
    gload_lds16(qk + qbase + (size_t)((kv0) + r1) * 2048 + kc1, (char*)Ks[buf] + ub1);    \
    gload_lds16(vt + vbase + (size_t)r0 * 2048 + (kv0) + (c0 << 3), (char*)Vs[buf] + ub0);\
    gload_lds16(vt + vbase + (size_t)r1 * 2048 + (kv0) + (c1 << 3), (char*)Vs[buf] + ub1);\
  } while (0)

  auto compute_tile = [&](const ushort_t* Kc, const ushort_t* Vc) {
    bf16x8 vf[2][4];
#pragma unroll
    for (int ks = 0; ks < 2; ++ks)
#pragma unroll
      for (int nb = 0; nb < 4; ++nb)
        vf[ks][nb] = *(const bf16x8*)(Vc + nb * 1024 + ll * 64 + (((ks * 4 + lg) ^ (ll & 7)) << 3));
#pragma unroll
    for (int pass = 0; pass < 2; ++pass) {
      const int cK = (lg ^ (ll & 7)) ^ (pass << 2);
      bf16x8 kf[4];
#pragma unroll
      for (int nb = 0; nb < 4; ++nb)
        kf[nb] = *(const bf16x8*)(Kc + nb * 1024 + ll * 64 + (cK << 3));
#pragma unroll
      for (int sub = 0; sub < 2; ++sub) {
        f32x4 s[4];
#pragma unroll
        for (int nb = 0; nb < 4; ++nb)
          s[nb] = mfma16(kf[nb], qf[pass][sub], zero4());  // D: row=k (4lg+i), col=q (ll)
        float part = 0.f;
#pragma unroll
        for (int nb = 0; nb < 4; ++nb) {
          float e0 = fexp2(s[nb][0]), e1 = fexp2(s[nb][1]);
          float e2 = fexp2(s[nb][2]), e3 = fexp2(s[nb][3]);
          part += (e0 + e1) + (e2 + e3);
          uint2 w;
          w.x = cvtpk(e0, e1);
          w.y = cvtpk(e2, e3);
          *(uint2*)(Pw + ll * 72 + nb * 16 + (lg << 2)) = w;  // P[q=ll][k=nb*16+4lg..+3]
        }
        lsum[pass][sub] += part;
#pragma unroll
        for (int ks = 0; ks < 2; ++ks) {
          bf16x8 pf = *(const bf16x8*)(Pw + ll * 72 + ks * 32 + (lg << 3));
#pragma unroll
          for (int nb = 0; nb < 4; ++nb)
            oacc[pass][sub][nb] = mfma16(pf, vf[ks][nb], oacc[pass][sub][nb]);
        }
      }
    }
  };

  STAGE(0, 0);
  __syncthreads();
  for (int tt = 0; tt < 16; ++tt) {
    STAGE(1, (tt * 2 + 1) * 64);
    compute_tile(Ks[0], Vs[0]);
    __syncthreads();
    if (tt < 15) STAGE(0, (tt * 2 + 2) * 64);
    compute_tile(Ks[1], Vs[1]);
    __syncthreads();
  }
#undef STAGE

#pragma unroll
  for (int sub = 0; sub < 2; ++sub) {
    float l1 = lsum[0][sub]; l1 += __shfl_xor(l1, 16); l1 += __shfl_xor(l1, 32);
    float l2 = lsum[1][sub]; l2 += __shfl_xor(l2, 16); l2 += __shfl_xor(l2, 32);
    float i1[4], i2[4];
#pragma unroll
    for (int j = 0; j < 4; ++j) {
      int src = (lane & 48) | ((lg << 2) + j);   // lane with ll == q-row
      i1[j] = 1.f / __shfl(l1, src);
      i2[j] = 1.f / __shfl(l2, src);
    }
    float ss[4] = {0.f, 0.f, 0.f, 0.f};
    f32x4 ov[4];
#pragma unroll
    for (int nb = 0; nb < 4; ++nb) {
#pragma unroll
      for (int j = 0; j < 4; ++j) {
        float x = oacc[0][sub][nb][j] * i1[j] - lam * (oacc[1][sub][nb][j] * i2[j]);
        ov[nb][j] = x;
        ss[j] += x * x;
      }
    }
#pragma unroll
    for (int mask = 1; mask < 16; mask <<= 1)
#pragma unroll
      for (int j = 0; j < 4; ++j) ss[j] += __shfl_xor(ss[j], mask);
    float nf[4];
#pragma unroll
    for (int j = 0; j < 4; ++j) nf[j] = rsqrtf(ss[j] * (1.f / 64.f) + 1e-5f);
    const size_t orow0 = (size_t)(b * 2048 + qt * 128 + wave * 32 + sub * 16);
#pragma unroll
    for (int nb = 0; nb < 4; ++nb) {
      int d = nb * 16 + ll;
      float sw = subln[d] * ONE_MINUS_LI;
#pragma unroll
      for (int j = 0; j < 4; ++j) {
        int r = (lg << 2) + j;
        o[(orow0 + r) * 1024 + (h << 6) + d] = f2bf(ov[nb][j] * nf[j] * sw);
      }
    }
  }
}

extern "C" void kernel_launch(void* const* d_in, const int* in_sizes, int n_in,
                              void* d_out, int out_size, void* d_ws, size_t ws_size,
                              hipStream_t stream) {
  const float* x      = (const float*)d_in[0];
  const float* W_qkv  = (const float*)d_in[1];
  const float* W_proj = (const float*)d_in[2];
  const float* b_proj = (const float*)d_in[3];
  const float* lq1    = (const float*)d_in[4];
  const float* lk1    = (const float*)d_in[5];
  const float* lq2    = (const float*)d_in[6];
  const float* lk2    = (const float*)d_in[7];
  const float* subln  = (const float*)d_in[8];

  char* ws = (char*)d_ws;
  ushort_t* xb     = (ushort_t*)(ws);                 //  8,388,608 B (4096x1024 bf16)
  ushort_t* qkb    = (ushort_t*)(ws + 8388608);       // 16,777,216 B (4096x2048 bf16, q|k)
  ushort_t* vtb    = (ushort_t*)(ws + 25165824);      //  8,388,608 B (V^T: [2*16*64][2048])
  ushort_t* wqkvT  = (ushort_t*)(ws + 33554432);      //  6,291,456 B (3072x1024 bf16)
  ushort_t* wprojT = (ushort_t*)(ws + 39845888);      //  2,097,152 B (1024x1024 bf16)
  ushort_t* ob     = (ushort_t*)(ws + 41943040);      //  8,388,608 B (4096x1024 bf16)

  cvt_f32_bf16<<<2048, 256, 0, stream>>>(x, xb, 4096 * 1024);
  transpose_to_bf16<<<dim3(96, 32), 256, 0, stream>>>(W_qkv, wqkvT, 1024, 3072);
  transpose_to_bf16<<<dim3(32, 32), 256, 0, stream>>>(W_proj, wprojT, 1024, 1024);
  gemm_bt<1><<<dim3(32, 24), 256, 0, stream>>>(xb, wqkvT, (void*)qkb, vtb, nullptr, 4096, 3072, 1024);
  diff_attn<<<dim3(16, 16, 2), 256, 0, stream>>>(qkb, vtb, ob, lq1, lk1, lq2, lk2, subln);
  gemm_bt<0><<<dim3(32, 8), 256, 0, stream>>>(ob, wprojT, d_out, nullptr, b_proj, 4096, 1024, 1024);
}